// Round 11
// baseline (120.729 us; speedup 1.0000x reference)
//
#include <hip/hip_runtime.h>
#include <math.h>

#define B 4
#define DEC 256
#define ENC 256
#define HDIM 512

// exp2(x*TANH_SCALE) == e^{2x};  tanh(x) = 1 - 2/(1+e^{2x})
#define TANH_SCALE 2.8853900817779268f
#define LOG2E 1.4426950408889634f

__device__ __forceinline__ float fast_exp2(float x) { return __builtin_amdgcn_exp2f(x); }
__device__ __forceinline__ float fast_rcp(float x)  { return __builtin_amdgcn_rcpf(x); }

typedef __attribute__((ext_vector_type(8))) short bf16x8;   // 8 bf16 = 4 VGPR
typedef __attribute__((ext_vector_type(4))) short bf16x4;
typedef __attribute__((ext_vector_type(4))) float f32x4;

__device__ __forceinline__ unsigned short bf16_rne(float x) {
    unsigned u = __float_as_uint(x);
    return (unsigned short)((u + 0x7FFFu + ((u >> 16) & 1u)) >> 16);
}
__device__ __forceinline__ float bf16_to_f(unsigned short h) {
    return __uint_as_float((unsigned)h << 16);
}

// Blocked-transpose W layout (shorts): ofs(m,k) = (m/16)*8192 + (k/8)*128 + (m%16)*8 + k%8
#define W_OFS(m, k) ((((long)(m) >> 4) << 13) + (((long)(k) >> 3) << 7) + (((m) & 15) << 3) + ((k) & 7))

// ---------------------------------------------------------------------------
// convert (verbatim R10): fp32 -> bf16 hi/lo split.
//  z=0/1: X (enc/dec) -> Xh/Xl row-major. 8 els/thread.
//  z=2/3: W half -> blocked-transpose layout (128B-segment writes).
// ---------------------------------------------------------------------------
__global__ __launch_bounds__(256) void convert_kernel(
    const float* __restrict__ enc, const float* __restrict__ dec,
    const float* __restrict__ Wmlp,
    unsigned short* __restrict__ Xh_e, unsigned short* __restrict__ Xl_e,
    unsigned short* __restrict__ Xh_d, unsigned short* __restrict__ Xl_d,
    unsigned short* __restrict__ Wh_e, unsigned short* __restrict__ Wl_e,
    unsigned short* __restrict__ Wh_d, unsigned short* __restrict__ Wl_d)
{
    const int tid = threadIdx.x, z = blockIdx.z;
    if (z < 2) {
        const float* X = z ? dec : enc;
        unsigned short* H = z ? Xh_d : Xh_e;
        unsigned short* L = z ? Xl_d : Xl_e;
        const long i8 = ((long)blockIdx.x * 256 + tid) * 8;
        float4 v0 = *(const float4*)(X + i8);
        float4 v1 = *(const float4*)(X + i8 + 4);
        float xs[8] = {v0.x, v0.y, v0.z, v0.w, v1.x, v1.y, v1.z, v1.w};
        bf16x8 hv, lv;
#pragma unroll
        for (int j = 0; j < 8; ++j) {
            unsigned short h = bf16_rne(xs[j]);
            hv[j] = (short)h;
            lv[j] = (short)bf16_rne(xs[j] - bf16_to_f(h));
        }
        *(bf16x8*)(H + i8) = hv;
        *(bf16x8*)(L + i8) = lv;
    } else {
        const float* Wsrc = Wmlp + (z == 3 ? (long)HDIM * HDIM : 0);
        unsigned short* H = (z == 3) ? Wh_d : Wh_e;
        unsigned short* L = (z == 3) ? Wl_d : Wl_e;
        const int t = blockIdx.x * 256 + tid;
        const int m = t & 511;
        const int k0 = (t >> 9) << 2;
        bf16x4 hv, lv;
#pragma unroll
        for (int j = 0; j < 4; ++j) {
            float x = Wsrc[(long)(k0 + j) * 512 + m];
            unsigned short h = bf16_rne(x);
            hv[j] = (short)h;
            lv[j] = (short)bf16_rne(x - bf16_to_f(h));
        }
        const long ofs = W_OFS(m, k0);
        *(bf16x4*)(H + ofs) = hv;
        *(bf16x4*)(L + ofs) = lv;
    }
}

// ---------------------------------------------------------------------------
// proj via MFMA (verbatim R10): wave = 16r x 32m (2 C-tiles), runtime K-loop
// with depth-1 ping-pong (bounded loads in flight), 4 acc chains, hi/lo
// 3-mfma scheme. grid (16, 16, 2) = 512 blocks.
// ---------------------------------------------------------------------------
__global__ __launch_bounds__(256) void proj_mfma_kernel(
    const unsigned short* __restrict__ Xh_e, const unsigned short* __restrict__ Xl_e,
    const unsigned short* __restrict__ Xh_d, const unsigned short* __restrict__ Xl_d,
    const unsigned short* __restrict__ Wh_e, const unsigned short* __restrict__ Wl_e,
    const unsigned short* __restrict__ Wh_d, const unsigned short* __restrict__ Wl_d,
    const float* __restrict__ bmlp,
    float* __restrict__ ET, float* __restrict__ Dmat)
{
    const int tid = threadIdx.x;
    const int wave = tid >> 6, lane = tid & 63;
    const int z = blockIdx.z;
    const int r0w = blockIdx.x * 64 + wave * 16;
    const int m0 = blockIdx.y * 32;
    const unsigned short* Xh = z ? Xh_d : Xh_e;
    const unsigned short* Xl = z ? Xl_d : Xl_e;
    const unsigned short* Wh = z ? Wh_d : Wh_e;
    const unsigned short* Wl = z ? Wl_d : Wl_e;

    const int col = lane & 15;
    const int quad = lane >> 4;

    const unsigned short* pah = Xh + (long)(r0w + col) * 512 + quad * 8;
    const unsigned short* pal = Xl + (long)(r0w + col) * 512 + quad * 8;
    const long bofs = ((long)(m0 >> 4) << 13) + (quad << 7) + (col << 3);
    const unsigned short* pb0h = Wh + bofs;
    const unsigned short* pb0l = Wl + bofs;
    const unsigned short* pb1h = Wh + bofs + 8192;
    const unsigned short* pb1l = Wl + bofs + 8192;

    f32x4 a0h = {0.f,0.f,0.f,0.f}, a0x = {0.f,0.f,0.f,0.f};
    f32x4 a1h = {0.f,0.f,0.f,0.f}, a1x = {0.f,0.f,0.f,0.f};

    bf16x8 Ah = *(const bf16x8*)pah,  Al = *(const bf16x8*)pal;
    bf16x8 B0h = *(const bf16x8*)pb0h, B0l = *(const bf16x8*)pb0l;
    bf16x8 B1h = *(const bf16x8*)pb1h, B1l = *(const bf16x8*)pb1l;

#pragma unroll 1
    for (int k0 = 0; k0 < 512; k0 += 32) {
        bf16x8 nAh = Ah, nAl = Al, nB0h = B0h, nB0l = B0l, nB1h = B1h, nB1l = B1l;
        if (k0 + 32 < 512) {
            nAh = *(const bf16x8*)(pah + k0 + 32);
            nAl = *(const bf16x8*)(pal + k0 + 32);
            const long ko = (long)(k0 + 32) << 4;
            nB0h = *(const bf16x8*)(pb0h + ko);
            nB0l = *(const bf16x8*)(pb0l + ko);
            nB1h = *(const bf16x8*)(pb1h + ko);
            nB1l = *(const bf16x8*)(pb1l + ko);
        }
        a0h = __builtin_amdgcn_mfma_f32_16x16x32_bf16(Ah, B0h, a0h, 0, 0, 0);
        a1h = __builtin_amdgcn_mfma_f32_16x16x32_bf16(Ah, B1h, a1h, 0, 0, 0);
        a0x = __builtin_amdgcn_mfma_f32_16x16x32_bf16(Ah, B0l, a0x, 0, 0, 0);
        a1x = __builtin_amdgcn_mfma_f32_16x16x32_bf16(Ah, B1l, a1x, 0, 0, 0);
        a0x = __builtin_amdgcn_mfma_f32_16x16x32_bf16(Al, B0h, a0x, 0, 0, 0);
        a1x = __builtin_amdgcn_mfma_f32_16x16x32_bf16(Al, B1h, a1x, 0, 0, 0);
        Ah = nAh; Al = nAl; B0h = nB0h; B0l = nB0l; B1h = nB1h; B1l = nB1l;
    }

    if (z == 0) {
        const int batch = r0w >> 8;
        const int e0 = (r0w & 255) + quad * 4;
        float* base = ET + (long)batch * HDIM * ENC;
        float4 v;
        v.x = fast_exp2((a0h[0] + a0x[0]) * TANH_SCALE);
        v.y = fast_exp2((a0h[1] + a0x[1]) * TANH_SCALE);
        v.z = fast_exp2((a0h[2] + a0x[2]) * TANH_SCALE);
        v.w = fast_exp2((a0h[3] + a0x[3]) * TANH_SCALE);
        *(float4*)&base[(long)(m0 + col) * ENC + e0] = v;
        v.x = fast_exp2((a1h[0] + a1x[0]) * TANH_SCALE);
        v.y = fast_exp2((a1h[1] + a1x[1]) * TANH_SCALE);
        v.z = fast_exp2((a1h[2] + a1x[2]) * TANH_SCALE);
        v.w = fast_exp2((a1h[3] + a1x[3]) * TANH_SCALE);
        *(float4*)&base[(long)(m0 + 16 + col) * ENC + e0] = v;
    } else {
        const float bq0 = bmlp[m0 + col];
        const float bq1 = bmlp[m0 + 16 + col];
        const int r = r0w + quad * 4;
#pragma unroll
        for (int i = 0; i < 4; ++i) {
            Dmat[(long)(r + i) * HDIM + m0 + col] =
                fast_exp2((a0h[i] + a0x[i] + bq0) * TANH_SCALE);
            Dmat[(long)(r + i) * HDIM + m0 + 16 + col] =
                fast_exp2((a1h[i] + a1x[i] + bq1) * TANH_SCALE);
        }
    }
}

// ---------------------------------------------------------------------------
// attn (merged back, R8-proven): thread = e, 2 d-rows/block, 512 blocks.
// D0/D1/wo staged in LDS (ds_read_b128 broadcast); E^T coalesced, 16-deep
// register prefetch; full softmax in-block. No `part` round-trip.
// ---------------------------------------------------------------------------
__global__ __launch_bounds__(256) void attn_kernel(
    const float* __restrict__ Dmat, const float* __restrict__ ET,
    const float* __restrict__ wo,
    const float* __restrict__ enc, const unsigned char* __restrict__ extm,
    float* __restrict__ attn_out)
{
    __shared__ __align__(16) float d0s[HDIM];
    __shared__ __align__(16) float d1s[HDIM];
    __shared__ __align__(16) float wos[HDIM];
    __shared__ float red[2][4][2];

    const int tid = threadIdx.x, lane = tid & 63, wave = tid >> 6;
    const int b = blockIdx.y, d0 = blockIdx.x * 2;

    const float* D0 = Dmat + ((long)b * DEC + d0) * HDIM;
    const float* ecol = ET + (long)b * HDIM * ENC + tid;

    *(float2*)&d0s[tid * 2] = *(const float2*)&D0[tid * 2];
    *(float2*)&d1s[tid * 2] = *(const float2*)&D0[HDIM + tid * 2];
    *(float2*)&wos[tid * 2] = *(const float2*)&wo[tid * 2];

    float ev[16], nv[16];
#pragma unroll
    for (int j = 0; j < 16; ++j) ev[j] = ecol[j * ENC];
    __syncthreads();

    float acc0 = 0.f, acc1 = 0.f;
    for (int m = 0; m < HDIM; m += 16) {
        if (m + 16 < HDIM) {
#pragma unroll
            for (int j = 0; j < 16; ++j) nv[j] = ecol[(m + 16 + j) * ENC];
        }
        float4 dv0[4], dv1[4], wv[4];
#pragma unroll
        for (int q = 0; q < 4; ++q) {
            dv0[q] = *(const float4*)&d0s[m + q * 4];
            dv1[q] = *(const float4*)&d1s[m + q * 4];
            wv[q]  = *(const float4*)&wos[m + q * 4];
        }
#pragma unroll
        for (int j = 0; j < 16; ++j) {
            float w  = ((const float*)&wv[j >> 2])[j & 3];
            float t0 = fmaf(ev[j], ((const float*)&dv0[j >> 2])[j & 3], 1.0f);
            float t1 = fmaf(ev[j], ((const float*)&dv1[j >> 2])[j & 3], 1.0f);
            acc0 = fmaf(w, fast_rcp(t0), acc0);
            acc1 = fmaf(w, fast_rcp(t1), acc1);
        }
#pragma unroll
        for (int j = 0; j < 16; ++j) ev[j] = nv[j];
    }

    const int e = tid;
    const bool pad = (enc[((long)b * ENC + e) * HDIM] == 0.0f);
    const bool x0m = extm[((long)(b * DEC) + d0) * ENC + e] != 0;
    const bool x1m = extm[((long)(b * DEC) + d0 + 1) * ENC + e] != 0;
    float l0 = (pad || x0m) ? -__builtin_inff() : -2.0f * acc0;
    float l1 = (pad || x1m) ? -__builtin_inff() : -2.0f * acc1;

    float m0 = l0, m1 = l1;
#pragma unroll
    for (int off = 32; off >= 1; off >>= 1) {
        m0 = fmaxf(m0, __shfl_xor(m0, off, 64));
        m1 = fmaxf(m1, __shfl_xor(m1, off, 64));
    }
    if (lane == 0) { red[0][wave][0] = m0; red[0][wave][1] = m1; }
    __syncthreads();
    const float gm0 = fmaxf(fmaxf(red[0][0][0], red[0][1][0]), fmaxf(red[0][2][0], red[0][3][0]));
    const float gm1 = fmaxf(fmaxf(red[0][0][1], red[0][1][1]), fmaxf(red[0][2][1], red[0][3][1]));
    float p0 = fast_exp2((l0 - gm0) * LOG2E);
    float p1 = fast_exp2((l1 - gm1) * LOG2E);
    float s0 = p0, s1 = p1;
#pragma unroll
    for (int off = 32; off >= 1; off >>= 1) {
        s0 += __shfl_xor(s0, off, 64);
        s1 += __shfl_xor(s1, off, 64);
    }
    if (lane == 0) { red[1][wave][0] = s0; red[1][wave][1] = s1; }
    __syncthreads();
    const float gs0 = red[1][0][0] + red[1][1][0] + red[1][2][0] + red[1][3][0];
    const float gs1 = red[1][0][1] + red[1][1][1] + red[1][2][1] + red[1][3][1];
    attn_out[((long)(b * DEC) + d0) * ENC + e] = p0 * fast_rcp(gs0);
    attn_out[((long)(b * DEC) + d0 + 1) * ENC + e] = p1 * fast_rcp(gs1);
}

// ---------------------------------------------------------------------------
// ctx v3 (verbatim R10, passing): 8 d-rows x 256-h stripe per block.
// ---------------------------------------------------------------------------
#define C5_LOADW(WB, KOFF)                                                  \
    _Pragma("unroll")                                                       \
    for (int kk = 0; kk < 8; ++kk)                                          \
        WB[kk] = *(const float4*)&We[(long)((KOFF) + kk) * HDIM];

#define C5_FMA(WB, KOFF)                                                    \
    _Pragma("unroll")                                                       \
    for (int q = 0; q < 2; ++q) {                                           \
        float4 xq0 = *(const float4*)&as8[r0l][(KOFF) + q * 4];             \
        float4 xq1 = *(const float4*)&as8[r0l + 1][(KOFF) + q * 4];         \
        _Pragma("unroll")                                                   \
        for (int kk = 0; kk < 4; ++kk) {                                    \
            float4 w = WB[q * 4 + kk];                                      \
            float xv0 = ((const float*)&xq0)[kk];                           \
            float xv1 = ((const float*)&xq1)[kk];                           \
            acc[0][0] = fmaf(xv0, w.x, acc[0][0]);                          \
            acc[0][1] = fmaf(xv0, w.y, acc[0][1]);                          \
            acc[0][2] = fmaf(xv0, w.z, acc[0][2]);                          \
            acc[0][3] = fmaf(xv0, w.w, acc[0][3]);                          \
            acc[1][0] = fmaf(xv1, w.x, acc[1][0]);                          \
            acc[1][1] = fmaf(xv1, w.y, acc[1][1]);                          \
            acc[1][2] = fmaf(xv1, w.z, acc[1][2]);                          \
            acc[1][3] = fmaf(xv1, w.w, acc[1][3]);                          \
        }                                                                   \
    }

__global__ __launch_bounds__(256) void context_kernel(
    const float* __restrict__ attn, const float* __restrict__ enc,
    float* __restrict__ ctx)
{
    __shared__ __align__(16) float as8[8][ENC];
    const int tid = threadIdx.x;
    const int tx = tid & 63, ty = tid >> 6;
    const int r0 = blockIdx.x * 8;
    const int b = r0 >> 8;
    const int h0 = blockIdx.y * 256 + tx * 4;
    const int r0l = ty * 2;
    const float* We = enc + (long)b * ENC * HDIM + h0;

    {
        const float* ag = attn + (long)r0 * ENC;
#pragma unroll
        for (int i = 0; i < 2; ++i) {
            int idx = (tid + i * 256) * 4;
            *(float4*)&as8[0][idx] = *(const float4*)&ag[idx];
        }
    }

    float acc[2][4] = {};
    float4 Wa[8], Wb[8];
    C5_LOADW(Wa, 0)
    __syncthreads();

    for (int k0 = 0; k0 < ENC; k0 += 16) {
        C5_LOADW(Wb, k0 + 8)
        C5_FMA(Wa, k0)
        if (k0 + 16 < ENC) { C5_LOADW(Wa, k0 + 16) }
        C5_FMA(Wb, k0 + 8)
    }

#pragma unroll
    for (int i = 0; i < 2; ++i)
        *(float4*)&ctx[(long)(r0 + r0l + i) * HDIM + h0] =
            make_float4(acc[i][0], acc[i][1], acc[i][2], acc[i][3]);
}

// ---------------------------------------------------------------------------
extern "C" void kernel_launch(void* const* d_in, const int* in_sizes, int n_in,
                              void* d_out, int out_size, void* d_ws, size_t ws_size,
                              hipStream_t stream) {
    const float* dec = (const float*)d_in[0];
    const float* enc = (const float*)d_in[1];
    const unsigned char* extm = (const unsigned char*)d_in[2];
    const float* Wmlp = (const float*)d_in[3];
    const float* bmlp = (const float*)d_in[4];
    const float* Wout = (const float*)d_in[5];
    // d_in[6] = b_out: additive constant, cancels in softmax

    float* ctx = (float*)d_out;                    // [B, DEC, H]
    float* attn = ctx + (size_t)B * DEC * HDIM;    // [B, DEC, ENC]

    const size_t F = (size_t)B * DEC * HDIM;       // 524288
    float* ET = (float*)d_ws;                      // [B][H][ENC] fp32
    float* Dmat = ET + F;                          // [B*DEC][H] fp32
    unsigned short* Xh_e = (unsigned short*)(Dmat + F);
    unsigned short* Xl_e = Xh_e + F;
    unsigned short* Xh_d = Xl_e + F;
    unsigned short* Xl_d = Xh_d + F;
    unsigned short* Wh_e = Xl_d + F;               // blocked-T layout, 512*512
    unsigned short* Wl_e = Wh_e + HDIM * HDIM;
    unsigned short* Wh_d = Wl_e + HDIM * HDIM;
    unsigned short* Wl_d = Wh_d + HDIM * HDIM;

    convert_kernel<<<dim3(256, 1, 4), 256, 0, stream>>>(
        enc, dec, Wmlp, Xh_e, Xl_e, Xh_d, Xl_d, Wh_e, Wl_e, Wh_d, Wl_d);
    proj_mfma_kernel<<<dim3(16, 16, 2), 256, 0, stream>>>(
        Xh_e, Xl_e, Xh_d, Xl_d, Wh_e, Wl_e, Wh_d, Wl_d, bmlp, ET, Dmat);
    attn_kernel<<<dim3(DEC / 2, B), 256, 0, stream>>>(Dmat, ET, Wout, enc, extm, attn);
    context_kernel<<<dim3(128, 2), 256, 0, stream>>>(attn, enc, ctx);
}